// Round 1
// baseline (224.886 us; speedup 1.0000x reference)
//
#include <hip/hip_runtime.h>
#include <hip/hip_bf16.h>

#define Mm 8
#define Nn 512
#define NEe 409
#define NIi 103
#define Bb 512
#define Dd 243
#define Tt 16
#define SPROW 640      // spike row bytes (i8): e[0:409) pad[409:512) i[512:615) pad[615:640)
#define WCROW 1152     // packed weight row bytes (i8): inter(512) | E-rec(512) | I-rec(128)
#define DEC_I 0.33333334f  // (float)(1.0 - 1.0/1.5)
#define NBLK 256
#define FLAGSTRIDE 16  // one flag per 64B cache line
#define FLAGINTS 8192  // full 32 KB flag region (zeroed every launch)
#define SPINMAX 1000000L

typedef int v4i __attribute__((ext_vector_type(4)));
union LV { long l[2]; v4i v; };

__device__ __forceinline__ float quantf(float w) {
    // fake_quant forward == clip(round-half-even(w), -8, 7)  (step = 1.0)
    float q = rintf(w);
    return fminf(fmaxf(q, -8.0f), 7.0f);
}

// ---------------- pack quantized recurrent weights as i8, 4 k's per thread ----------
// (r11/r13-verified; separate kernel so pack keeps its own register budget — r15 lesson)
// Block 0 additionally zeroes the sync-flag region: the k_ticks neighborhood protocol
// requires flags < 1 at launch. Stale flags (==15 from a prior launch / graph replay)
// or positive poison make every wait pass immediately -> data race -> the tripwire
// divergence seen in the failed bench. Stream order guarantees this completes before
// k_ticks; the kernel boundary guarantees visibility.
__global__ void k_pack(const float* __restrict__ Wint, const float* __restrict__ WEE,
                       const float* __restrict__ WEI, const float* __restrict__ WIE,
                       const float* __restrict__ WII, signed char* __restrict__ Wc,
                       int* __restrict__ flags) {
    if (blockIdx.x == 0) {
        for (int i = threadIdx.x; i < FLAGINTS; i += 256) flags[i] = 0;
    }
    int q = blockIdx.x * 256 + threadIdx.x;          // quad index
    if (q >= (Mm * Nn * WCROW) / 4) return;
    int k0 = (q * 4) % WCROW;
    int n  = ((q * 4) / WCROW) & (Nn - 1);
    int m  = (q * 4) / (WCROW * Nn);
    char out4[4];
#pragma unroll
    for (int j = 0; j < 4; ++j) {
        int k = k0 + j;
        float w = 0.0f;
        if (k < 512) {
            if (k < NEe) w = Wint[((((m + 7) & 7) * Nn) + n) * NEe + k];
        } else if (k < 1024) {
            int jj = k - 512;
            if (jj < NEe) w = (n < NEe) ? WEE[((m * NEe) + n) * NEe + jj]
                                        : WEI[((m * NIi) + (n - NEe)) * NEe + jj];
        } else {
            int jj = k - 1024;
            if (jj < NIi) w = (n < NEe) ? WIE[((m * NEe) + n) * NIi + jj]
                                        : WII[((m * NIi) + (n - NEe)) * NIi + jj];
        }
        out4[j] = (signed char)(int)quantf(w);
    }
    *(int*)&Wc[q * 4] = *(int*)out4;
}

// ---------------- ext_proj = x @ qW_in^T + b_in  (r8-verified chunk-64, verbatim) ----
__global__ void k_ext(const float* __restrict__ x, const float* __restrict__ Win,
                      const float* __restrict__ bin, float* __restrict__ ext) {
    __shared__ float xs[64][68];
    __shared__ float wsm[64][68];
    const int bid = blockIdx.x;          // 512 blocks: m(8) x bt(8) x nt(8)
    const int m  = bid >> 6;
    const int bt = (bid >> 3) & 7;
    const int nt = bid & 7;
    const int b0 = bt * 64, n0 = nt * 64;
    const int t = threadIdx.x;
    const int tb4 = (t & 15) * 4;
    const int tn4 = (t >> 4) * 4;
    const int sr = t >> 2;
    const int sc = (t & 3) * 16;
    float c[4][4];
#pragma unroll
    for (int i = 0; i < 4; ++i)
#pragma unroll
        for (int j = 0; j < 4; ++j) c[i][j] = 0.0f;

    for (int d0 = 0; d0 < Dd; d0 += 64) {
#pragma unroll
        for (int j = 0; j < 16; ++j) {
            int d = d0 + sc + j;
            float xv = 0.0f, wv = 0.0f;
            if (d < Dd) {
                xv = x[(b0 + sr) * Dd + d];
                wv = quantf(Win[((m * Nn) + n0 + sr) * Dd + d]);
            }
            xs[sc + j][sr] = xv;
            wsm[sc + j][sr] = wv;
        }
        __syncthreads();
        const int dmax = min(64, Dd - d0);
        for (int d = 0; d < dmax; ++d) {
            float4 av = *(const float4*)&xs[d][tb4];
            float4 wv = *(const float4*)&wsm[d][tn4];
            float a[4] = {av.x, av.y, av.z, av.w};
            float wq[4] = {wv.x, wv.y, wv.z, wv.w};
#pragma unroll
            for (int i = 0; i < 4; ++i)
#pragma unroll
                for (int j = 0; j < 4; ++j)
                    c[i][j] = fmaf(a[i], wq[j], c[i][j]);
        }
        __syncthreads();
    }
#pragma unroll
    for (int i = 0; i < 4; ++i)
#pragma unroll
        for (int j = 0; j < 4; ++j) {
            float val = __fadd_rn(c[i][j], bin[m * Nn + n0 + tn4 + j]);
            ext[(size_t)(m * Bb + b0 + tb4 + i) * Nn + n0 + tn4 + j] = val;
        }
}

// ---------------- persistent 16-tick LIF: r13 structure, BK=256 K-chunks ------------
// 256 blocks x 512 thr, tile 64b x 128n, neighborhood dataflow sync (r13-verified).
// BK 128->256 halves loop barriers (9->5 chunks: [0,256)[256,512)[512,768)[768,1024)
// [1024,1152-half)); segment flushes after chunk1 (inter), chunk3 (E), epilogue (I)
// keep the reference's exact fp32 add order. LDS 96 KB, 1 block/CU, swizzle key
// widened to 4 bits (cnk ^ row&15 / (ks>>4)+quad ^ li) — same 2-way-free banks.
__global__ void __launch_bounds__(512, 2)
k_ticks(const signed char* __restrict__ Wc,
        signed char* __restrict__ Sp0,
        signed char* __restrict__ Sp1,
        const float* __restrict__ ext,
        float* __restrict__ out,
        int* __restrict__ flags) {
    __shared__ __align__(16) signed char sA[2][64][256];    // 32 KB
    __shared__ __align__(16) signed char sB[2][128][256];   // 64 KB

    const int wg = blockIdx.x;           // 256: m(8) x bt(8) x nt(4)
    const int m  = wg & 7;               // mesh -> XCD affinity heuristic
    const int bt = (wg >> 3) & 7;
    const int nt = wg >> 6;              // 0..3
    const int b0 = bt * 64;
    const int n0 = nt * 128;
    const int pm = (m + 7) & 7;
    const int nm = (m + 1) & 7;

    const int tid  = threadIdx.x;        // 0..511
    const int w    = tid >> 6;           // 0..7
    const int lane = tid & 63;
    const int bh   = w & 1;              // 32-row half of b-tile
    const int nh   = w >> 1;             // 0..3: 32-col slice of n-tile
    const int quad = lane >> 4;
    const int li   = lane & 15;          // 4-bit swizzle key

    // wait-set flag index for tid<12: mesh {pm,m,nm}[tid>>2], nt'=tid&3, same bt
    int waitIdx = 0;
    if (tid < 12) {
        int g  = tid >> 2;
        int mm = (g == 0) ? pm : ((g == 1) ? m : nm);
        waitIdx = (((tid & 3) << 6) | (bt << 3) | mm) * FLAGSTRIDE;
    }

    // staging coords (BK=256): A 2 chunks/thread (64 rows x 16), B 4 (128 rows x 16)
    int rowA[2], cnkA[2], gcolA[2], scolA[2];
#pragma unroll
    for (int j = 0; j < 2; ++j) {
        int ch = tid + j * 512;
        rowA[j]  = ch >> 4;
        cnkA[j]  = ch & 15;
        gcolA[j] = cnkA[j] * 16;
        scolA[j] = (cnkA[j] ^ (rowA[j] & 15)) * 16;
    }
    int rowB[4], cnkB[4], gcolB[4], scolB[4];
#pragma unroll
    for (int j = 0; j < 4; ++j) {
        int ch = tid + j * 512;
        rowB[j]  = ch >> 4;
        cnkB[j]  = ch & 15;
        gcolB[j] = cnkB[j] * 16;
        scolB[j] = (cnkB[j] ^ (rowB[j] & 15)) * 16;
    }

    float decs[2]; int offs[2]; int nels[2];
#pragma unroll
    for (int tn = 0; tn < 2; ++tn) {
        int n = n0 + nh * 32 + tn * 16 + li;
        nels[tn] = n;
        decs[tn] = (n < NEe) ? 0.5f : DEC_I;
        offs[tn] = (n < NEe) ? n : (n + 103);   // i-region of spike row starts at 512
    }
    const int bbase = b0 + bh * 32;

    const signed char* WcBase = Wc + (size_t)(m * Nn + n0) * WCROW;

    // per-thread persistent state in registers for all 16 ticks
    float extr[2][2][4];
#pragma unroll
    for (int tb = 0; tb < 2; ++tb)
#pragma unroll
        for (int tn = 0; tn < 2; ++tn)
#pragma unroll
            for (int r = 0; r < 4; ++r) {
                int b = bbase + tb * 16 + quad * 4 + r;
                extr[tb][tn][r] = ext[(size_t)(m * Bb + b) * Nn + nels[tn]];
            }
    float vmem[2][2][4];
    int cnt[2][2];
#pragma unroll
    for (int tb = 0; tb < 2; ++tb)
#pragma unroll
        for (int tn = 0; tn < 2; ++tn) {
            cnt[tb][tn] = 0;
#pragma unroll
            for (int r = 0; r < 4; ++r) vmem[tb][tn][r] = 0.0f;
        }

    // tick-0 pad-zeroing (r9/r11-verified): nt==0 blocks zero the pad bytes of their
    // 64 rows in both buffers; visible to consumers via this block's flag(1) post
    if (nt == 0) {
        for (int idx = tid; idx < 64 * 128 * 2; idx += 512) {
            int bufsel = idx >> 13;
            int rr = (idx >> 7) & 63;
            int p  = idx & 127;
            int off = (p < 103) ? (409 + p) : (615 + (p - 103));
            signed char* base = (bufsel ? Sp1 : Sp0) + (size_t)(m * Bb + b0 + rr) * SPROW + off;
            __hip_atomic_store(base, (signed char)0, __ATOMIC_RELAXED, __HIP_MEMORY_SCOPE_AGENT);
        }
    }

    for (int t = 0; t < Tt; ++t) {
        signed char* SR = (t & 1) ? Sp1 : Sp0;
        signed char* SW = (t & 1) ? Sp0 : Sp1;
        signed char* AbasePrev = SR + (size_t)(pm * Bb + b0) * SPROW;
        signed char* AbaseOwn  = SR + (size_t)(m  * Bb + b0) * SPROW;

        // neighborhood wait: 12 flags {pm,m,nm} x nt' at level t (t>=1).
        if (t > 0) {
            if (tid < 12) {
                long spin = 0;
                while (__hip_atomic_load(&flags[waitIdx],
                                         __ATOMIC_RELAXED, __HIP_MEMORY_SCOPE_AGENT) < t) {
                    __builtin_amdgcn_s_sleep(2);
                    if (++spin > SPINMAX) break;   // bail: wrong answer beats a hang
                }
            }
            __syncthreads();
        }

        float c[2][2][4];

        if (t == 0) {
            // spikes all zero: c = ((ext + 0) + 0) + 0, exact fadd chain as GEMM path
#pragma unroll
            for (int tb = 0; tb < 2; ++tb)
#pragma unroll
                for (int tn = 0; tn < 2; ++tn)
#pragma unroll
                    for (int r = 0; r < 4; ++r)
                        c[tb][tn][r] = __fadd_rn(__fadd_rn(__fadd_rn(extr[tb][tn][r], 0.0f), 0.0f), 0.0f);
        } else {
            v4i acc[2][2];
#pragma unroll
            for (int tb = 0; tb < 2; ++tb)
#pragma unroll
                for (int tn = 0; tn < 2; ++tn) acc[tb][tn] = (v4i){0, 0, 0, 0};

            // stage chunk 0 ([0,256) of prev-mesh e segment); A via agent atomics (L3)
#pragma unroll
            for (int j = 0; j < 2; ++j) {
                long* ap = (long*)(AbasePrev + (size_t)rowA[j] * SPROW + gcolA[j]);
                LV tmp;
                tmp.l[0] = __hip_atomic_load(ap,     __ATOMIC_RELAXED, __HIP_MEMORY_SCOPE_AGENT);
                tmp.l[1] = __hip_atomic_load(ap + 1, __ATOMIC_RELAXED, __HIP_MEMORY_SCOPE_AGENT);
                *(v4i*)&sA[0][rowA[j]][scolA[j]] = tmp.v;
            }
#pragma unroll
            for (int j = 0; j < 4; ++j)
                *(v4i*)&sB[0][rowB[j]][scolB[j]] =
                    *(const v4i*)(WcBase + (size_t)rowB[j] * WCROW + gcolB[j]);
            __syncthreads();

            // main chunks 0..3 (full 256-wide), prefetch next (chunk 4 is half-width)
            for (int it = 0; it < 4; ++it) {
                const int buf = it & 1;
                const int k0 = (it + 1) * 256;          // 256,512,768,1024
                signed char* ab; int ko;
                if (k0 < 512) { ab = AbasePrev; ko = k0; }
                else          { ab = AbaseOwn;  ko = k0 - 512; }
                const int kw = (it == 3) ? 128 : 256;   // chunk 4 has 128 valid bytes
                v4i nA[2], nB[4];
                bool ldA[2], ldB[4];
#pragma unroll
                for (int j = 0; j < 2; ++j) {
                    ldA[j] = (gcolA[j] < kw);
                    if (ldA[j]) {
                        long* ap = (long*)(ab + (size_t)rowA[j] * SPROW + ko + gcolA[j]);
                        LV tmp;
                        tmp.l[0] = __hip_atomic_load(ap,     __ATOMIC_RELAXED, __HIP_MEMORY_SCOPE_AGENT);
                        tmp.l[1] = __hip_atomic_load(ap + 1, __ATOMIC_RELAXED, __HIP_MEMORY_SCOPE_AGENT);
                        nA[j] = tmp.v;
                    }
                }
#pragma unroll
                for (int j = 0; j < 4; ++j) {
                    ldB[j] = (gcolB[j] < kw);
                    if (ldB[j])
                        nB[j] = *(const v4i*)(WcBase + (size_t)rowB[j] * WCROW + k0 + gcolB[j]);
                }
                // compute current chunk: 4 k-steps of 64 (swizzled fragment reads)
#pragma unroll
                for (int ks = 0; ks < 256; ks += 64) {
                    const int c0 = (((ks >> 4) + quad) ^ li) * 16;
                    v4i af0 = *(const v4i*)&sA[buf][bh * 32 + li][c0];
                    v4i af1 = *(const v4i*)&sA[buf][bh * 32 + 16 + li][c0];
#pragma unroll
                    for (int tn = 0; tn < 2; ++tn) {
                        v4i bfr = *(const v4i*)&sB[buf][nh * 32 + tn * 16 + li][c0];
                        acc[0][tn] = __builtin_amdgcn_mfma_i32_16x16x64_i8(af0, bfr, acc[0][tn], 0, 0, 0);
                        acc[1][tn] = __builtin_amdgcn_mfma_i32_16x16x64_i8(af1, bfr, acc[1][tn], 0, 0, 0);
                    }
                }
                const int nb = buf ^ 1;
#pragma unroll
                for (int j = 0; j < 2; ++j)
                    if (ldA[j]) *(v4i*)&sA[nb][rowA[j]][scolA[j]] = nA[j];
#pragma unroll
                for (int j = 0; j < 4; ++j)
                    if (ldB[j]) *(v4i*)&sB[nb][rowB[j]][scolB[j]] = nB[j];
                __syncthreads();
                // segment flushes: exact fp32 add order c = ((ext+inter)+E)+I
                if (it == 1) {
#pragma unroll
                    for (int tb = 0; tb < 2; ++tb)
#pragma unroll
                        for (int tn = 0; tn < 2; ++tn) {
#pragma unroll
                            for (int r = 0; r < 4; ++r)
                                c[tb][tn][r] = __fadd_rn(extr[tb][tn][r], (float)acc[tb][tn][r]);
                            acc[tb][tn] = (v4i){0, 0, 0, 0};
                        }
                } else if (it == 3) {
#pragma unroll
                    for (int tb = 0; tb < 2; ++tb)
#pragma unroll
                        for (int tn = 0; tn < 2; ++tn) {
#pragma unroll
                            for (int r = 0; r < 4; ++r)
                                c[tb][tn][r] = __fadd_rn(c[tb][tn][r], (float)acc[tb][tn][r]);
                            acc[tb][tn] = (v4i){0, 0, 0, 0};
                        }
                }
            }
            // epilogue: chunk 4 ([1024,1152), 128 valid bytes -> 2 k-steps), buf 0
#pragma unroll
            for (int ks = 0; ks < 128; ks += 64) {
                const int c0 = (((ks >> 4) + quad) ^ li) * 16;
                v4i af0 = *(const v4i*)&sA[0][bh * 32 + li][c0];
                v4i af1 = *(const v4i*)&sA[0][bh * 32 + 16 + li][c0];
#pragma unroll
                for (int tn = 0; tn < 2; ++tn) {
                    v4i bfr = *(const v4i*)&sB[0][nh * 32 + tn * 16 + li][c0];
                    acc[0][tn] = __builtin_amdgcn_mfma_i32_16x16x64_i8(af0, bfr, acc[0][tn], 0, 0, 0);
                    acc[1][tn] = __builtin_amdgcn_mfma_i32_16x16x64_i8(af1, bfr, acc[1][tn], 0, 0, 0);
                }
            }
#pragma unroll
            for (int tb = 0; tb < 2; ++tb)
#pragma unroll
                for (int tn = 0; tn < 2; ++tn)
#pragma unroll
                    for (int r = 0; r < 4; ++r)
                        c[tb][tn][r] = __fadd_rn(c[tb][tn][r], (float)acc[tb][tn][r]);
        }

        // LIF update, exact np op order: v' = (v*decay) + c; spike iff v' >= 1.0
        // spikes published via agent-scope atomic byte stores (write-through)
#pragma unroll
        for (int tb = 0; tb < 2; ++tb)
#pragma unroll
            for (int tn = 0; tn < 2; ++tn)
#pragma unroll
                for (int r = 0; r < 4; ++r) {
                    float vn = __fadd_rn(__fmul_rn(vmem[tb][tn][r], decs[tn]), c[tb][tn][r]);
                    int s = (vn >= 1.0f) ? 1 : 0;
                    vmem[tb][tn][r] = s ? 0.0f : vn;
                    cnt[tb][tn] += s << (r * 8);
                    if (t < Tt - 1) {
                        int b = bbase + tb * 16 + quad * 4 + r;
                        signed char* sp = SW + (size_t)(m * Bb + b) * SPROW + offs[tn];
                        __hip_atomic_store(sp, (signed char)s,
                                           __ATOMIC_RELAXED, __HIP_MEMORY_SCOPE_AGENT);
                    }
                }
        // post completion flag for tick t (covers this tick's reads AND writes)
        if (t < Tt - 1) {
            __syncthreads();              // vmcnt(0): spike atomics + LDS use complete
            if (tid == 0)
                __hip_atomic_store(&flags[wg * FLAGSTRIDE], t + 1,
                                   __ATOMIC_RELAXED, __HIP_MEMORY_SCOPE_AGENT);
        }
    }

    // out[b][m*N + n] = spike count (single write at the end)
#pragma unroll
    for (int tb = 0; tb < 2; ++tb)
#pragma unroll
        for (int tn = 0; tn < 2; ++tn)
#pragma unroll
            for (int r = 0; r < 4; ++r) {
                int b = bbase + tb * 16 + quad * 4 + r;
                out[(size_t)b * (Mm * Nn) + m * Nn + nels[tn]] =
                    (float)((cnt[tb][tn] >> (r * 8)) & 0xff);
            }
}

extern "C" void kernel_launch(void* const* d_in, const int* in_sizes, int n_in,
                              void* d_out, int out_size, void* d_ws, size_t ws_size,
                              hipStream_t stream) {
    const float* x    = (const float*)d_in[0];
    const float* Win  = (const float*)d_in[1];
    const float* bin  = (const float*)d_in[2];
    const float* Wint = (const float*)d_in[3];
    const float* WEE  = (const float*)d_in[4];
    const float* WEI  = (const float*)d_in[5];
    const float* WIE  = (const float*)d_in[6];
    const float* WII  = (const float*)d_in[7];
    float* out = (float*)d_out;

    char* ws = (char*)d_ws;
    signed char* Wc  = (signed char*)ws;                       // 8*512*1152 = 4,718,592
    signed char* Sp0 = (signed char*)(ws + 4718592);           // 8*512*640  = 2,621,440
    signed char* Sp1 = Sp0 + 2621440;
    int* flags = (int*)(ws + 4718592 + 2 * 2621440);           // 256*64 B (zeroed in k_pack blk0)
    float* extw = (float*)(ws + 4718592 + 2 * 2621440 + 32768);  // 8,388,608

    k_pack<<<(Mm * Nn * WCROW / 4 + 255) / 256, 256, 0, stream>>>(Wint, WEE, WEI, WIE, WII, Wc, flags);
    k_ext<<<512, 256, 0, stream>>>(x, Win, bin, extw);
    k_ticks<<<NBLK, 512, 0, stream>>>(Wc, Sp0, Sp1, (const float*)extw, out, flags);
}

// Round 2
// 203.425 us; speedup vs baseline: 1.1055x; 1.1055x over previous
//
#include <hip/hip_runtime.h>
#include <hip/hip_bf16.h>

#define Mm 8
#define Nn 512
#define NEe 409
#define NIi 103
#define Bb 512
#define Dd 243
#define Tt 16
#define SPB 96         // bit-packed spike row bytes: e-bits[0,64) | i-bits[64,80) | pad[80,96)
#define WCROW 1152     // packed weight row bytes (i8): inter(512) | E-rec(512) | I-rec(128, data at [1049,1152))
#define DEC_I 0.33333334f  // (float)(1.0 - 1.0/1.5)
#define NBLK 256
#define FLAGSTRIDE 16  // one flag per 64B cache line
#define FLAGINTS 8192  // full 32 KB flag region (zeroed every launch)
#define SPINMAX 1000000L
#define ABROW 176      // LDS A-bit row stride (mult 16; word-stride 44 -> 2-way-free banks)

typedef int v4i __attribute__((ext_vector_type(4)));

__device__ __forceinline__ float quantf(float w) {
    // fake_quant forward == clip(round-half-even(w), -8, 7)  (step = 1.0)
    float q = rintf(w);
    return fminf(fmaxf(q, -8.0f), 7.0f);
}

// nibble -> 4 bytes of 0/1: (nib * 0x204081) & 0x01010101 places bit j at byte j.
// d = dword of the bit-plane containing this fragment's 16 bits at offset qsh.
__device__ __forceinline__ v4i unpack16(unsigned int dl, unsigned int dh, bool qhi, int qsh) {
    unsigned int d = qhi ? dh : dl;
    v4i r;
    r[0] = (int)((((d >> qsh) & 0xFu) * 0x00204081u) & 0x01010101u);
    r[1] = (int)((((d >> (qsh + 4)) & 0xFu) * 0x00204081u) & 0x01010101u);
    r[2] = (int)((((d >> (qsh + 8)) & 0xFu) * 0x00204081u) & 0x01010101u);
    r[3] = (int)((((d >> (qsh + 12)) & 0xFu) * 0x00204081u) & 0x01010101u);
    return r;
}

// ---------------- pack quantized recurrent weights as i8, 4 k's per thread ----------
// K layout: [0,512) inter (prev-mesh e, valid k<409), [512,1024) E-rec (valid jj<409),
// [1024,1152) I-rec REBASED to jj = k-1049 (so bit-packed i-plane halfwords stay
// 16-bit aligned; bits/weights at k in [1024,1049) are zero).
// Block 0 additionally zeroes the sync-flag region (launch-invariance; see r0 note).
__global__ void k_pack(const float* __restrict__ Wint, const float* __restrict__ WEE,
                       const float* __restrict__ WEI, const float* __restrict__ WIE,
                       const float* __restrict__ WII, signed char* __restrict__ Wc,
                       int* __restrict__ flags) {
    if (blockIdx.x == 0) {
        for (int i = threadIdx.x; i < FLAGINTS; i += 256) flags[i] = 0;
    }
    int q = blockIdx.x * 256 + threadIdx.x;          // quad index
    if (q >= (Mm * Nn * WCROW) / 4) return;
    int k0 = (q * 4) % WCROW;
    int n  = ((q * 4) / WCROW) & (Nn - 1);
    int m  = (q * 4) / (WCROW * Nn);
    char out4[4];
#pragma unroll
    for (int j = 0; j < 4; ++j) {
        int k = k0 + j;
        float w = 0.0f;
        if (k < 512) {
            if (k < NEe) w = Wint[((((m + 7) & 7) * Nn) + n) * NEe + k];
        } else if (k < 1024) {
            int jj = k - 512;
            if (jj < NEe) w = (n < NEe) ? WEE[((m * NEe) + n) * NEe + jj]
                                        : WEI[((m * NIi) + (n - NEe)) * NEe + jj];
        } else {
            int jj = k - 1049;                       // rebased I segment
            if (jj >= 0 && jj < NIi) w = (n < NEe) ? WIE[((m * NEe) + n) * NIi + jj]
                                        : WII[((m * NIi) + (n - NEe)) * NIi + jj];
        }
        out4[j] = (signed char)(int)quantf(w);
    }
    *(int*)&Wc[q * 4] = *(int*)out4;
}

// ---------------- ext_proj = x @ qW_in^T + b_in  (r8-verified chunk-64, verbatim) ----
__global__ void k_ext(const float* __restrict__ x, const float* __restrict__ Win,
                      const float* __restrict__ bin, float* __restrict__ ext) {
    __shared__ float xs[64][68];
    __shared__ float wsm[64][68];
    const int bid = blockIdx.x;          // 512 blocks: m(8) x bt(8) x nt(8)
    const int m  = bid >> 6;
    const int bt = (bid >> 3) & 7;
    const int nt = bid & 7;
    const int b0 = bt * 64, n0 = nt * 64;
    const int t = threadIdx.x;
    const int tb4 = (t & 15) * 4;
    const int tn4 = (t >> 4) * 4;
    const int sr = t >> 2;
    const int sc = (t & 3) * 16;
    float c[4][4];
#pragma unroll
    for (int i = 0; i < 4; ++i)
#pragma unroll
        for (int j = 0; j < 4; ++j) c[i][j] = 0.0f;

    for (int d0 = 0; d0 < Dd; d0 += 64) {
#pragma unroll
        for (int j = 0; j < 16; ++j) {
            int d = d0 + sc + j;
            float xv = 0.0f, wv = 0.0f;
            if (d < Dd) {
                xv = x[(b0 + sr) * Dd + d];
                wv = quantf(Win[((m * Nn) + n0 + sr) * Dd + d]);
            }
            xs[sc + j][sr] = xv;
            wsm[sc + j][sr] = wv;
        }
        __syncthreads();
        const int dmax = min(64, Dd - d0);
        for (int d = 0; d < dmax; ++d) {
            float4 av = *(const float4*)&xs[d][tb4];
            float4 wv = *(const float4*)&wsm[d][tn4];
            float a[4] = {av.x, av.y, av.z, av.w};
            float wq[4] = {wv.x, wv.y, wv.z, wv.w};
#pragma unroll
            for (int i = 0; i < 4; ++i)
#pragma unroll
                for (int j = 0; j < 4; ++j)
                    c[i][j] = fmaf(a[i], wq[j], c[i][j]);
        }
        __syncthreads();
    }
#pragma unroll
    for (int i = 0; i < 4; ++i)
#pragma unroll
        for (int j = 0; j < 4; ++j) {
            float val = __fadd_rn(c[i][j], bin[m * Nn + n0 + tn4 + j]);
            ext[(size_t)(m * Bb + b0 + tb4 + i) * Nn + n0 + tn4 + j] = val;
        }
}

// ---------------- persistent 16-tick LIF: B-resident LDS + bit-packed spikes --------
// 256 blocks x 512 thr, tile 64b x 128n, neighborhood dataflow sync (unchanged).
// Weights (tick-invariant) preloaded ONCE into LDS (144 KB, XOR-swizzled 16B granules,
// same conflict-free scheme as the staged version). Spikes exchanged BIT-PACKED
// (96 B/row): per tick a block stages 9 KB of A-bits into LDS, unpacks nibble->i8
// in VALU; spike writes are ballot-packed ushort stores. Pad K-ranges are don't-care
// (B columns there are zero). Barriers: 3/tick (was 7). LDS 155 KB, 1 block/CU.
__global__ void __launch_bounds__(512, 2)
k_ticks(const signed char* __restrict__ Wc,
        unsigned char* __restrict__ Sp0,
        unsigned char* __restrict__ Sp1,
        const float* __restrict__ ext,
        float* __restrict__ out,
        int* __restrict__ flags) {
    __shared__ __align__(16) signed char sB[128 * WCROW];     // 144 KB resident weights
    __shared__ __align__(16) unsigned char sAb[64 * ABROW];   // 11 KB per-tick spike bits

    const int wg = blockIdx.x;           // 256: m(8) x bt(8) x nt(4)
    const int m  = wg & 7;               // mesh -> XCD affinity heuristic
    const int bt = (wg >> 3) & 7;
    const int nt = wg >> 6;              // 0..3
    const int b0 = bt * 64;
    const int n0 = nt * 128;
    const int pm = (m + 7) & 7;
    const int nm = (m + 1) & 7;

    const int tid  = threadIdx.x;        // 0..511
    const int w    = tid >> 6;           // 0..7
    const int lane = tid & 63;
    const int bh   = w & 1;              // 32-row half of b-tile
    const int nh   = w >> 1;             // 0..3: 32-col slice of n-tile
    const int quad = lane >> 4;
    const int li   = lane & 15;

    // wait-set flag index for tid<12: mesh {pm,m,nm}[tid>>2], nt'=tid&3, same bt
    int waitIdx = 0;
    if (tid < 12) {
        int g  = tid >> 2;
        int mm = (g == 0) ? pm : ((g == 1) ? m : nm);
        waitIdx = (((tid & 3) << 6) | (bt << 3) | mm) * FLAGSTRIDE;
    }

    // ---- one-time B preload: 9216 16B granules, XOR-swizzled within 256B spans ----
    const signed char* WcBase = Wc + (size_t)(m * Nn + n0) * WCROW;
#pragma unroll
    for (int j = 0; j < 18; ++j) {
        int task = tid + j * 512;                 // exactly 9216 = 512*18
        int row = task / 72, gg = task % 72;
        v4i v = *(const v4i*)(WcBase + (size_t)row * WCROW + gg * 16);
        int gs = (gg < 64) ? ((gg & 48) | ((gg ^ row) & 15))
                           : (64 + ((gg ^ row) & 7));
        *(v4i*)&sB[row * WCROW + gs * 16] = v;
    }

    float decs[2]; int nels[2];
    int styp[2], soff[2];                // store type per tn: 0/1 = plain @soff, 2 = mixed
#pragma unroll
    for (int tn = 0; tn < 2; ++tn) {
        int n = n0 + nh * 32 + tn * 16 + li;
        nels[tn] = n;
        decs[tn] = (n < NEe) ? 0.5f : DEC_I;
        int nb = n0 + nh * 32 + tn * 16;         // wave-uniform halfword base
        if (nb < 400)      { styp[tn] = 0; soff[tn] = nb >> 3; }          // pure E
        else if (nb == 400){ styp[tn] = 2; soff[tn] = 50; }               // mixed E/I
        else               { styp[tn] = 1; soff[tn] = 64 + ((nb - 384) >> 3); } // pure I
    }
    const int bbase = b0 + bh * 32;

    // per-thread persistent state in registers for all 16 ticks
    float extr[2][2][4];
#pragma unroll
    for (int tb = 0; tb < 2; ++tb)
#pragma unroll
        for (int tn = 0; tn < 2; ++tn)
#pragma unroll
            for (int r = 0; r < 4; ++r) {
                int b = bbase + tb * 16 + quad * 4 + r;
                extr[tb][tn][r] = ext[(size_t)(m * Bb + b) * Nn + nels[tn]];
            }
    float vmem[2][2][4];
    int cnt[2][2];
#pragma unroll
    for (int tb = 0; tb < 2; ++tb)
#pragma unroll
        for (int tn = 0; tn < 2; ++tn) {
            cnt[tb][tn] = 0;
#pragma unroll
            for (int r = 0; r < 4; ++r) vmem[tb][tn][r] = 0.0f;
        }

    // init-zero of never-stored bit ranges (hygiene; B columns there are zero anyway):
    // e-bits [416,512) = bytes [52,64), i-bits [0,16) = bytes [64,66), both buffers.
    if (nt == 0 && tid < 128) {
        int buf = tid >> 6, rr = tid & 63;
        unsigned char* base = (buf ? Sp1 : Sp0) + (size_t)(m * Bb + b0 + rr) * SPB;
        __hip_atomic_store((unsigned int*)(base + 52), 0u, __ATOMIC_RELAXED, __HIP_MEMORY_SCOPE_AGENT);
        __hip_atomic_store((unsigned int*)(base + 56), 0u, __ATOMIC_RELAXED, __HIP_MEMORY_SCOPE_AGENT);
        __hip_atomic_store((unsigned int*)(base + 60), 0u, __ATOMIC_RELAXED, __HIP_MEMORY_SCOPE_AGENT);
        __hip_atomic_store((unsigned short*)(base + 64), (unsigned short)0, __ATOMIC_RELAXED, __HIP_MEMORY_SCOPE_AGENT);
    }

    const bool qhi = (quad >= 2);
    const int qsh = (quad & 1) << 4;
    const int r0base = (bh * 32 + li) * ABROW;
    const int r1base = (bh * 32 + 16 + li) * ABROW;

    for (int t = 0; t < Tt; ++t) {
        unsigned char* SR = (t & 1) ? Sp1 : Sp0;
        unsigned char* SW = (t & 1) ? Sp0 : Sp1;

        // neighborhood wait: 12 flags {pm,m,nm} x nt' at level t (t>=1).
        if (t > 0) {
            if (tid < 12) {
                long spin = 0;
                while (__hip_atomic_load(&flags[waitIdx],
                                         __ATOMIC_RELAXED, __HIP_MEMORY_SCOPE_AGENT) < t) {
                    __builtin_amdgcn_s_sleep(2);
                    if (++spin > SPINMAX) break;   // bail: wrong answer beats a hang
                }
            }
            __syncthreads();
        }

        float c[2][2][4];

        if (t == 0) {
            // spikes all zero: c = ((ext + 0) + 0) + 0, exact fadd chain as GEMM path
#pragma unroll
            for (int tb = 0; tb < 2; ++tb)
#pragma unroll
                for (int tn = 0; tn < 2; ++tn)
#pragma unroll
                    for (int r = 0; r < 4; ++r)
                        c[tb][tn][r] = __fadd_rn(__fadd_rn(__fadd_rn(extr[tb][tn][r], 0.0f), 0.0f), 0.0f);
        } else {
            // ---- stage A-bits: LDS row = [prev-e 64B | own-e 64B | own-i 16B | pad] ----
            const unsigned char* PrevRow = SR + (size_t)(pm * Bb + b0) * SPB;
            const unsigned char* OwnRow  = SR + (size_t)(m  * Bb + b0) * SPB;
#pragma unroll
            for (int j = 0; j < 3; ++j) {
                int task = tid + j * 512;              // 1152 u64 tasks
                if (task < 1152) {
                    int row = task / 18, s = task % 18;
                    const unsigned char* src;
                    int dstoff;
                    if (s < 8)       { src = PrevRow + (size_t)row * SPB + s * 8;            dstoff = s * 8; }
                    else if (s < 16) { src = OwnRow  + (size_t)row * SPB + (s - 8) * 8;      dstoff = s * 8; }
                    else             { src = OwnRow  + (size_t)row * SPB + 64 + (s - 16) * 8; dstoff = 128 + (s - 16) * 8; }
                    unsigned long long vb = __hip_atomic_load((const unsigned long long*)src,
                                               __ATOMIC_RELAXED, __HIP_MEMORY_SCOPE_AGENT);
                    *(unsigned long long*)&sAb[row * ABROW + dstoff] = vb;
                }
            }
            __syncthreads();

            v4i acc[2][2];
#pragma unroll
            for (int tb = 0; tb < 2; ++tb)
#pragma unroll
                for (int tn = 0; tn < 2; ++tn) acc[tb][tn] = (v4i){0, 0, 0, 0};

            // ---- 4 full 256-wide K-chunks, no barriers (B resident, A in regs) ----
#pragma unroll
            for (int ch = 0; ch < 4; ++ch) {
                const int cb = ch << 8;
                v4i a0lo = *(const v4i*)&sAb[r0base + (cb >> 3)];
                v4i a0hi = *(const v4i*)&sAb[r0base + (cb >> 3) + 16];
                v4i a1lo = *(const v4i*)&sAb[r1base + (cb >> 3)];
                v4i a1hi = *(const v4i*)&sAb[r1base + (cb >> 3) + 16];
#pragma unroll
                for (int ks = 0; ks < 256; ks += 64) {
                    v4i s0 = (ks < 128) ? a0lo : a0hi;
                    v4i s1 = (ks < 128) ? a1lo : a1hi;
                    const int D0 = ((ks >> 6) & 1) ? 2 : 0;
                    v4i af0 = unpack16((unsigned int)s0[D0], (unsigned int)s0[D0 + 1], qhi, qsh);
                    v4i af1 = unpack16((unsigned int)s1[D0], (unsigned int)s1[D0 + 1], qhi, qsh);
                    const int gs = (cb >> 4) + ((((ks >> 4) + quad) ^ li) & 15);
#pragma unroll
                    for (int tn = 0; tn < 2; ++tn) {
                        const v4i bfr = *(const v4i*)&sB[(nh * 32 + tn * 16 + li) * WCROW + gs * 16];
                        acc[0][tn] = __builtin_amdgcn_mfma_i32_16x16x64_i8(af0, bfr, acc[0][tn], 0, 0, 0);
                        acc[1][tn] = __builtin_amdgcn_mfma_i32_16x16x64_i8(af1, bfr, acc[1][tn], 0, 0, 0);
                    }
                }
                // segment flushes: exact fp32 add order c = ((ext+inter)+E)+I
                if (ch == 1) {
#pragma unroll
                    for (int tb = 0; tb < 2; ++tb)
#pragma unroll
                        for (int tn = 0; tn < 2; ++tn) {
#pragma unroll
                            for (int r = 0; r < 4; ++r)
                                c[tb][tn][r] = __fadd_rn(extr[tb][tn][r], (float)acc[tb][tn][r]);
                            acc[tb][tn] = (v4i){0, 0, 0, 0};
                        }
                } else if (ch == 3) {
#pragma unroll
                    for (int tb = 0; tb < 2; ++tb)
#pragma unroll
                        for (int tn = 0; tn < 2; ++tn) {
#pragma unroll
                            for (int r = 0; r < 4; ++r)
                                c[tb][tn][r] = __fadd_rn(c[tb][tn][r], (float)acc[tb][tn][r]);
                            acc[tb][tn] = (v4i){0, 0, 0, 0};
                        }
                }
            }
            // ---- epilogue: I segment, K [1024,1152) = i-plane bits [0,128) ----
            {
                v4i e0 = *(const v4i*)&sAb[r0base + 128];
                v4i e1 = *(const v4i*)&sAb[r1base + 128];
#pragma unroll
                for (int ks = 0; ks < 128; ks += 64) {
                    const int D0 = (ks >> 6) ? 2 : 0;
                    v4i af0 = unpack16((unsigned int)e0[D0], (unsigned int)e0[D0 + 1], qhi, qsh);
                    v4i af1 = unpack16((unsigned int)e1[D0], (unsigned int)e1[D0 + 1], qhi, qsh);
                    const int gs = 64 + ((((ks >> 4) + quad) ^ li) & 7);
#pragma unroll
                    for (int tn = 0; tn < 2; ++tn) {
                        const v4i bfr = *(const v4i*)&sB[(nh * 32 + tn * 16 + li) * WCROW + gs * 16];
                        acc[0][tn] = __builtin_amdgcn_mfma_i32_16x16x64_i8(af0, bfr, acc[0][tn], 0, 0, 0);
                        acc[1][tn] = __builtin_amdgcn_mfma_i32_16x16x64_i8(af1, bfr, acc[1][tn], 0, 0, 0);
                    }
                }
            }
#pragma unroll
            for (int tb = 0; tb < 2; ++tb)
#pragma unroll
                for (int tn = 0; tn < 2; ++tn)
#pragma unroll
                    for (int r = 0; r < 4; ++r)
                        c[tb][tn][r] = __fadd_rn(c[tb][tn][r], (float)acc[tb][tn][r]);
        }

        // LIF update, exact np op order: v' = (v*decay) + c; spike iff v' >= 1.0
        int snow[2][2] = {{0, 0}, {0, 0}};
#pragma unroll
        for (int tb = 0; tb < 2; ++tb)
#pragma unroll
            for (int tn = 0; tn < 2; ++tn)
#pragma unroll
                for (int r = 0; r < 4; ++r) {
                    float vn = __fadd_rn(__fmul_rn(vmem[tb][tn][r], decs[tn]), c[tb][tn][r]);
                    int s = (vn >= 1.0f) ? 1 : 0;
                    vmem[tb][tn][r] = s ? 0.0f : vn;
                    cnt[tb][tn] += s << (r * 8);
                    snow[tb][tn] |= s << r;
                }

        // ballot-packed spike publish: one ushort per (quad-row, 16-neuron group)
        if (t < Tt - 1) {
#pragma unroll
            for (int tb = 0; tb < 2; ++tb)
#pragma unroll
                for (int tn = 0; tn < 2; ++tn)
#pragma unroll
                    for (int r = 0; r < 4; ++r) {
                        unsigned long long mk = __ballot((snow[tb][tn] >> r) & 1);
                        if (li == 0) {   // 4 lanes, one per quad
                            unsigned short v = (unsigned short)(mk >> (unsigned)(quad << 4));
                            int row = bbase + tb * 16 + quad * 4 + r;
                            unsigned char* rb = SW + (size_t)(m * Bb + row) * SPB;
                            if (styp[tn] != 2) {
                                __hip_atomic_store((unsigned short*)(rb + soff[tn]), v,
                                                   __ATOMIC_RELAXED, __HIP_MEMORY_SCOPE_AGENT);
                            } else {
                                // mixed group (n 400..415): E bits li<=8, I bits li>=9
                                __hip_atomic_store((unsigned short*)(rb + 50),
                                                   (unsigned short)(v & 0x01FF),
                                                   __ATOMIC_RELAXED, __HIP_MEMORY_SCOPE_AGENT);
                                __hip_atomic_store((unsigned short*)(rb + 66),
                                                   (unsigned short)(v & 0xFE00),
                                                   __ATOMIC_RELAXED, __HIP_MEMORY_SCOPE_AGENT);
                            }
                        }
                    }
        }

        // post completion flag for tick t (covers this tick's reads AND writes)
        if (t < Tt - 1) {
            __syncthreads();              // drains spike stores + sAb reads
            if (tid == 0)
                __hip_atomic_store(&flags[wg * FLAGSTRIDE], t + 1,
                                   __ATOMIC_RELAXED, __HIP_MEMORY_SCOPE_AGENT);
        }
    }

    // out[b][m*N + n] = spike count (single write at the end)
#pragma unroll
    for (int tb = 0; tb < 2; ++tb)
#pragma unroll
        for (int tn = 0; tn < 2; ++tn)
#pragma unroll
            for (int r = 0; r < 4; ++r) {
                int b = bbase + tb * 16 + quad * 4 + r;
                out[(size_t)b * (Mm * Nn) + m * Nn + nels[tn]] =
                    (float)((cnt[tb][tn] >> (r * 8)) & 0xff);
            }
}

extern "C" void kernel_launch(void* const* d_in, const int* in_sizes, int n_in,
                              void* d_out, int out_size, void* d_ws, size_t ws_size,
                              hipStream_t stream) {
    const float* x    = (const float*)d_in[0];
    const float* Win  = (const float*)d_in[1];
    const float* bin  = (const float*)d_in[2];
    const float* Wint = (const float*)d_in[3];
    const float* WEE  = (const float*)d_in[4];
    const float* WEI  = (const float*)d_in[5];
    const float* WIE  = (const float*)d_in[6];
    const float* WII  = (const float*)d_in[7];
    float* out = (float*)d_out;

    char* ws = (char*)d_ws;
    signed char* Wc    = (signed char*)ws;                     // 8*512*1152 = 4,718,592
    unsigned char* Sp0 = (unsigned char*)(ws + 4718592);       // 8*512*96 = 393,216 (slot 2.6MB)
    unsigned char* Sp1 = Sp0 + 2621440;
    int* flags = (int*)(ws + 4718592 + 2 * 2621440);           // 32 KB (zeroed in k_pack blk0)
    float* extw = (float*)(ws + 4718592 + 2 * 2621440 + 32768);  // 8,388,608

    k_pack<<<(Mm * Nn * WCROW / 4 + 255) / 256, 256, 0, stream>>>(Wint, WEE, WEI, WIE, WII, Wc, flags);
    k_ext<<<512, 256, 0, stream>>>(x, Win, bin, extw);
    k_ticks<<<NBLK, 512, 0, stream>>>(Wc, Sp0, Sp1, (const float*)extw, out, flags);
}